// Round 7
// baseline (324.436 us; speedup 1.0000x reference)
//
#include <hip/hip_runtime.h>
#include <hip/hip_bf16.h>
#include <stdint.h>

typedef __bf16 bf16x8 __attribute__((ext_vector_type(8)));
typedef float f32x16 __attribute__((ext_vector_type(16)));
typedef unsigned short u16x8 __attribute__((ext_vector_type(8)));

#define AS1 __attribute__((address_space(1)))
#define AS3 __attribute__((address_space(3)))

__constant__ float c_nf4[16] = {
    -1.0f, -0.6961928009986877f, -0.5250730514526367f, -0.39491748809814453f,
    -0.28444138169288635f, -0.18477343022823334f, -0.09105003625154495f, 0.0f,
    0.07958029955625534f, 0.16093020141124725f, 0.24611230194568634f,
    0.33791524171829224f, 0.44070982933044434f, 0.5626170039176941f,
    0.7229568362236023f, 1.0f};

__device__ __forceinline__ unsigned short f2bf_rne(float f) {
  unsigned int u = __builtin_bit_cast(unsigned int, f);
  u += 0x7FFFu + ((u >> 16) & 1u);
  return (unsigned short)(u >> 16);
}

// Fused prep: chunks [0, w8) dequant+LoRA-fold W; chunks [w8, w8+x8) cvt x.
__global__ __launch_bounds__(256) void k_prep(
    const int* __restrict__ q, const float* __restrict__ scale,
    const float* __restrict__ lA, const float* __restrict__ lB,
    const float* __restrict__ x, unsigned short* __restrict__ w,
    unsigned short* __restrict__ xb, int IN, int shIN, int R,
    long w8, long x8) {
  long idx = (long)blockIdx.x * 256 + threadIdx.x;
  if (idx < w8) {
    long e0 = idx * 8;
    int o = (int)(e0 >> shIN);
    int i0 = (int)(e0 & (IN - 1));
    float s = scale[e0 >> 6];
    const int* qp = q + e0;
    int4 qa = *(const int4*)qp;
    int4 qb = *(const int4*)(qp + 4);
    float v[8];
    v[0] = c_nf4[qa.x & 15] * s; v[1] = c_nf4[qa.y & 15] * s;
    v[2] = c_nf4[qa.z & 15] * s; v[3] = c_nf4[qa.w & 15] * s;
    v[4] = c_nf4[qb.x & 15] * s; v[5] = c_nf4[qb.y & 15] * s;
    v[6] = c_nf4[qb.z & 15] * s; v[7] = c_nf4[qb.w & 15] * s;
    for (int r = 0; r < R; ++r) {
      float br = 4.0f * lB[o * R + r];
      const float* ap = lA + (long)r * IN + i0;
      float4 a0 = *(const float4*)ap;
      float4 a1 = *(const float4*)(ap + 4);
      v[0] += br * a0.x; v[1] += br * a0.y; v[2] += br * a0.z; v[3] += br * a0.w;
      v[4] += br * a1.x; v[5] += br * a1.y; v[6] += br * a1.z; v[7] += br * a1.w;
    }
    u16x8 pk;
#pragma unroll
    for (int j = 0; j < 8; ++j) pk[j] = f2bf_rne(v[j]);
    *(u16x8*)(w + e0) = pk;
  } else {
    long i2 = idx - w8;
    if (i2 >= x8) return;
    long e0 = i2 * 8;
    float4 a0 = *(const float4*)(x + e0);
    float4 a1 = *(const float4*)(x + e0 + 4);
    u16x8 pk;
    pk[0] = f2bf_rne(a0.x); pk[1] = f2bf_rne(a0.y);
    pk[2] = f2bf_rne(a0.z); pk[3] = f2bf_rne(a0.w);
    pk[4] = f2bf_rne(a1.x); pk[5] = f2bf_rne(a1.y);
    pk[6] = f2bf_rne(a1.z); pk[7] = f2bf_rne(a1.w);
    *(u16x8*)(xb + e0) = pk;
  }
}

// ---------------------------------------------------------------------------
// 256x256 tile, BK=64, 8 waves (2M x 4N), 4 phases/tile, reads-early
// (R6 schedule, verified), MFMA shape = 32x32x16 bf16 (13% lower pipe floor
// vs 16x16x32, half the instruction count). Per phase: one quadrant =
// 2 mb x 4 kq = 8 MFMAs; 8 A-reads + 4 B-reads (identical LDS traffic).
// A/B frag: row(col)=lane&31, k=(lane>>5)*8+i. C/D: col=lane&31,
// row=(reg&3)+8*(reg>>2)+4*(lane>>5).
// ---------------------------------------------------------------------------
__global__ __launch_bounds__(512, 2) void k_gemm_256(
    const unsigned short* __restrict__ Xb, const unsigned short* __restrict__ Wb,
    const float* __restrict__ bias, float* __restrict__ out,
    int M, int N, int K) {
  __shared__ char smem[131072];
  const int tid = threadIdx.x;
  const int wid = tid >> 6;
  const int lane = tid & 63;
  const int wr = wid >> 2;
  const int wc = wid & 3;
  const int wcl = wc & 1;
  const int l31 = lane & 31;
  const int l32 = lane >> 5;
  const int w7 = l31 & 7;

  // reader bases: byte-col(kq) = (kq*32 + l32*16) ^ (w7<<4)
  //             = ((kq ^ (w7>>1))<<5) + ((l32 ^ (w7&1))<<4)   (carry-free XOR)
  int baseA[4], baseB[4];
#pragma unroll
  for (int kq = 0; kq < 4; ++kq) {
    const int colk = ((kq ^ (w7 >> 1)) << 5) + ((l32 ^ (w7 & 1)) << 4);
    baseA[kq] = wr * 16384 + l31 * 128 + colk;
    baseB[kq] = 65536 + (wc >> 1) * 16384 + wcl * 8192 + l31 * 128 + colk;
  }

  int bid = blockIdx.x;
  const int nwg = gridDim.x;
  if ((nwg & 7) == 0) { const int cpx = nwg >> 3; bid = (bid & 7) * cpx + (bid >> 3); }
  const int nbn = N >> 8;
  const int m0 = (bid / nbn) << 8;
  const int n0 = (bid % nbn) << 8;

  // per-lane pre-swizzled global source offsets for staging (unchanged layout)
  int rowj[2], gcj[2];
#pragma unroll
  for (int j = 0; j < 2; ++j) {
    const int lo = wid * 2048 + j * 1024 + lane * 16;
    const int row = lo >> 7;
    const int ls = lo ^ ((row & 7) << 4);
    rowj[j] = row;
    gcj[j] = (ls & 127) >> 1;
  }
  const size_t halfstep = (size_t)128 * K;
  const unsigned short* pSA0[2]; const unsigned short* pSA1[2];
  const unsigned short* pSB0[2]; const unsigned short* pSB1[2];
#pragma unroll
  for (int j = 0; j < 2; ++j) {
    pSA0[j] = Xb + (size_t)(m0 + rowj[j]) * K + gcj[j];
    pSA1[j] = pSA0[j] + halfstep;
    pSB0[j] = Wb + (size_t)(n0 + rowj[j]) * K + gcj[j];
    pSB1[j] = pSB0[j] + halfstep;
  }

#define ST_A(bufl, h, coff)                                                          \
  {                                                                                  \
    __builtin_amdgcn_global_load_lds((const AS1 void*)(pSA##h[0] + (coff)),          \
        (AS3 void*)(smem + (bufl) * 32768 + (h) * 16384 + wid * 2048), 16, 0, 0);    \
    __builtin_amdgcn_global_load_lds((const AS1 void*)(pSA##h[1] + (coff)),          \
        (AS3 void*)(smem + (bufl) * 32768 + (h) * 16384 + wid * 2048 + 1024),        \
        16, 0, 0);                                                                   \
  }
#define ST_B(bufl, h, coff)                                                          \
  {                                                                                  \
    __builtin_amdgcn_global_load_lds((const AS1 void*)(pSB##h[0] + (coff)),          \
        (AS3 void*)(smem + 65536 + (bufl) * 32768 + (h) * 16384 + wid * 2048),       \
        16, 0, 0);                                                                   \
    __builtin_amdgcn_global_load_lds((const AS1 void*)(pSB##h[1] + (coff)),          \
        (AS3 void*)(smem + 65536 + (bufl) * 32768 + (h) * 16384 + wid * 2048 + 1024),\
        16, 0, 0);                                                                   \
  }

  bf16x8 afA[2][4], afB[2][4], b0[4], b1[4];
  f32x16 acc[4][2];
#pragma unroll
  for (int i = 0; i < 4; ++i)
#pragma unroll
    for (int j = 0; j < 2; ++j) acc[i][j] = (f32x16)0.0f;

#define RD_A(bufl, mq, dst)                                                          \
  _Pragma("unroll") for (int mb2 = 0; mb2 < 2; ++mb2)                                \
  _Pragma("unroll") for (int kq = 0; kq < 4; ++kq)                                   \
      dst[mb2][kq] = *(const bf16x8*)(smem + baseA[kq] +                             \
                                      ((bufl) * 32768 + (mq) * 8192 + mb2 * 4096));  \
  __builtin_amdgcn_sched_barrier(0);
#define RD_B(bufl, q, arr)                                                           \
  _Pragma("unroll") for (int kq = 0; kq < 4; ++kq)                                   \
      arr[kq] = *(const bf16x8*)(smem + baseB[kq] +                                  \
                                 ((bufl) * 32768 + (q) * 4096));                     \
  __builtin_amdgcn_sched_barrier(0);
#define MFMA_Q(mq, q, A, arr)                                                        \
  _Pragma("unroll") for (int kq = 0; kq < 4; ++kq)                                   \
  _Pragma("unroll") for (int mb2 = 0; mb2 < 2; ++mb2)                                \
      acc[(mq)*2+mb2][q] = __builtin_amdgcn_mfma_f32_32x32x16_bf16(                  \
          A[mb2][kq], arr[kq], acc[(mq)*2+mb2][q], 0, 0, 0);

#define BAR __builtin_amdgcn_s_barrier()
#define PRIO1 __builtin_amdgcn_s_setprio(1)
#define PRIO0 __builtin_amdgcn_s_setprio(0)
#define LGK0                                               \
  {                                                        \
    asm volatile("s_waitcnt lgkmcnt(0)" ::: "memory");     \
    __builtin_amdgcn_sched_barrier(0);                     \
  }
#define VM4 asm volatile("s_waitcnt vmcnt(4)" ::: "memory")
#define VM8 asm volatile("s_waitcnt vmcnt(8)" ::: "memory")

  // Reads-early subtile: phase = [wait; MFMA; next-phase ops; BAR]
#define SUBTILE(bufl, SC)                                                            \
  /* p0 */                                                                           \
  LGK0; PRIO1; MFMA_Q(0, 0, afA, b0) PRIO0;                                          \
  RD_B(bufl, 1, b1)                                                                  \
  BAR;                                                                               \
  /* p1 */                                                                           \
  LGK0; PRIO1; MFMA_Q(0, 1, afA, b1) PRIO0;                                          \
  RD_A(bufl, 1, afB)                                                                 \
  BAR;                                                                               \
  /* p2: B of bufl fully consumed (b1 done p1-LGK0) -> stage B(t+2) */               \
  LGK0; PRIO1; MFMA_Q(1, 0, afB, b0) PRIO0;                                          \
  ST_B(bufl, 0, SC) ST_B(bufl, 1, SC)                                                \
  VM4;                                                                               \
  BAR;                                                                               \
  /* p3: A of bufl consumed -> stage A(t+2); pre-read next tile's afA,b0 */          \
  PRIO1; MFMA_Q(1, 1, afB, b1) PRIO0;                                                \
  ST_A(bufl, 0, SC) ST_A(bufl, 1, SC)                                                \
  RD_A((bufl) ^ 1, 0, afA)                                                           \
  RD_B((bufl) ^ 1, 0, b0)                                                            \
  BAR;

  const int NT = K >> 6;

  // prologue: stage tile0->buf0, tile1->buf1; drain tile0; pre-read afA,b0
  ST_A(0, 0, 0) ST_A(0, 1, 0) ST_B(0, 0, 0) ST_B(0, 1, 0)
  ST_A(1, 0, 64) ST_A(1, 1, 64) ST_B(1, 0, 64) ST_B(1, 1, 64)
  VM8;
  BAR;
  RD_A(0, 0, afA)
  RD_B(0, 0, b0)
#pragma unroll
  for (int j = 0; j < 2; ++j) { pSA0[j] += 128; pSA1[j] += 128; pSB0[j] += 128; pSB1[j] += 128; }

  for (int t = 0; t < NT; t += 2) {
    SUBTILE(0, 0)
    SUBTILE(1, 64)
    if (t + 4 < NT) {
#pragma unroll
      for (int j = 0; j < 2; ++j) { pSA0[j] += 128; pSA1[j] += 128; pSB0[j] += 128; pSB1[j] += 128; }
    }
  }

  // epilogue: 32x32 C/D layout: col=lane&31, row=(reg&3)+8*(reg>>2)+4*(lane>>5)
#pragma unroll
  for (int nb = 0; nb < 2; ++nb) {
    const int col = n0 + wc * 64 + nb * 32 + l31;
    const float bv = bias[col];
#pragma unroll
    for (int mb = 0; mb < 4; ++mb) {
      const int rbase = m0 + wr * 128 + mb * 32 + 4 * l32;
#pragma unroll
      for (int reg = 0; reg < 16; ++reg) {
        const int row = rbase + (reg & 3) + 8 * (reg >> 2);
        out[(size_t)row * N + col] = acc[mb][nb][reg] + bv;
      }
    }
  }
#undef ST_A
#undef ST_B
#undef RD_A
#undef RD_B
#undef MFMA_Q
#undef BAR
#undef PRIO1
#undef PRIO0
#undef LGK0
#undef VM4
#undef VM8
#undef SUBTILE
}

extern "C" void kernel_launch(void* const* d_in, const int* in_sizes, int n_in,
                              void* d_out, int out_size, void* d_ws, size_t ws_size,
                              hipStream_t stream) {
  const float* x = (const float*)d_in[0];
  const int* qw = (const int*)d_in[1];
  const float* qs = (const float*)d_in[2];
  const float* bias = (const float*)d_in[3];
  const float* lA = (const float*)d_in[4];
  const float* lB = (const float*)d_in[5];
  float* out = (float*)d_out;

  const int OUT = in_sizes[3];
  const long qn = (long)in_sizes[1];
  const int IN = (int)(qn / OUT);
  const int R = in_sizes[5] / OUT;
  const long xn = (long)in_sizes[0];
  const int M = (int)(xn / IN);
  const int N = OUT, K = IN;

  unsigned short* Wb = (unsigned short*)d_ws;   // OUT*IN bf16
  unsigned short* Xb = Wb + qn;                 // M*IN bf16

  const int shIN = 31 - __builtin_clz((unsigned)IN);

  const long w8 = qn / 8;
  const long x8 = xn / 8;
  const long nchunks = w8 + x8;
  k_prep<<<(int)((nchunks + 255) / 256), 256, 0, stream>>>(
      qw, qs, lA, lB, x, Wb, Xb, IN, shIN, R, w8, x8);

  dim3 grid((M / 256) * (N / 256));
  k_gemm_256<<<grid, 512, 0, stream>>>(Xb, Wb, bias, out, M, N, K);
}